// Round 1
// 1047.929 us; speedup vs baseline: 1.1579x; 1.1579x over previous
//
#include <hip/hip_runtime.h>
#include <hip/hip_bf16.h>
#include <math.h>

// Problem constants
constexpr int B_ = 16, N_ = 196, D_ = 128, Q_ = 65536;
constexpr int M_ = B_ * N_;            // 3136 query rows
constexpr float TEMP_INV = 5.0f;       // 1/0.2
constexpr float SHIFT = 5.0f;          // logits <= 1/T = 5 exactly (cosine <= 1)

typedef __attribute__((ext_vector_type(8))) short short8;
typedef __attribute__((ext_vector_type(4))) float floatx4;

// round-to-nearest-even f32 -> bf16 (deterministic, no NaN inputs here)
__device__ inline ushort f2bf(float x) {
    union { float f; unsigned u; } v; v.f = x;
    unsigned r = (v.u + 0x7FFFu + ((v.u >> 16) & 1u)) >> 16;
    return (ushort)r;
}

// ---------------------------------------------------------------------------
// Kernel 1: L2-normalize queue rows, store bf16 [Q][128]. One wave per row.
__global__ void norm_queue_kernel(const float* __restrict__ queue,
                                  ushort* __restrict__ queue_bf) {
    int wave = threadIdx.x >> 6;
    int lane = threadIdx.x & 63;
    int row = blockIdx.x * 4 + wave;
    const float2* src = (const float2*)(queue + (size_t)row * 128);
    float2 v = src[lane];
    float ss = v.x * v.x + v.y * v.y;
#pragma unroll
    for (int off = 32; off; off >>= 1) ss += __shfl_xor(ss, off);
    float rinv = 1.0f / fmaxf(sqrtf(ss), 1e-12f);
    ushort2 o;
    o.x = f2bf(v.x * rinv);
    o.y = f2bf(v.y * rinv);
    ((ushort2*)(queue_bf + (size_t)row * 128))[lane] = o;
}

// ---------------------------------------------------------------------------
// Kernel 2: L2-normalize q rows (bf16 + f32) and k rows (f32). One wave/row.
__global__ void norm_qk_kernel(const float* __restrict__ d1,
                               const float* __restrict__ d2,
                               ushort* __restrict__ q_bf,
                               float* __restrict__ q_f,
                               float* __restrict__ k_f) {
    int wave = threadIdx.x >> 6;
    int lane = threadIdx.x & 63;
    int row = blockIdx.x * 4 + wave;          // 0..6271
    bool isQ = row < M_;
    int r = isQ ? row : row - M_;
    const float2* src = (const float2*)((isQ ? d1 : d2) + (size_t)r * 128);
    float2 v = src[lane];
    float ss = v.x * v.x + v.y * v.y;
#pragma unroll
    for (int off = 32; off; off >>= 1) ss += __shfl_xor(ss, off);
    float rinv = 1.0f / fmaxf(sqrtf(ss), 1e-12f);
    float2 o; o.x = v.x * rinv; o.y = v.y * rinv;
    if (isQ) {
        ((float2*)(q_f + (size_t)r * 128))[lane] = o;
        ushort2 ob; ob.x = f2bf(o.x); ob.y = f2bf(o.y);
        ((ushort2*)(q_bf + (size_t)r * 128))[lane] = ob;
    } else {
        ((float2*)(k_f + (size_t)r * 128))[lane] = o;
    }
}

// ---------------------------------------------------------------------------
// Kernel 3: pos_sim[b,n] = max_m dot(q_n[b,n], k_n[b,m]) * (1/T)
// One 256-thread block per (b,n); thread t handles candidate m=t (N_=196<256).
__global__ void possim_kernel(const float* __restrict__ q_f,
                              const float* __restrict__ k_f,
                              float* __restrict__ pos_out) {
    __shared__ __align__(16) float qs[128];
    __shared__ float red[256];
    int bn = blockIdx.x;
    int b = bn / N_;
    int t = threadIdx.x;
    if (t < 128) qs[t] = q_f[(size_t)bn * 128 + t];
    __syncthreads();
    float best = -1e30f;
    if (t < N_) {
        const float4* kr = (const float4*)(k_f + ((size_t)b * N_ + t) * 128);
        const float4* qv = (const float4*)qs;
        float dot = 0.f;
#pragma unroll
        for (int i = 0; i < 32; i++) {
            float4 kk = kr[i]; float4 qq = qv[i];
            dot += kk.x * qq.x + kk.y * qq.y + kk.z * qq.z + kk.w * qq.w;
        }
        best = dot;
    }
    red[t] = best;
    __syncthreads();
    for (int s = 128; s; s >>= 1) {
        if (t < s) red[t] = fmaxf(red[t], red[t + s]);
        __syncthreads();
    }
    if (t == 0) pos_out[bn] = red[0] * TEMP_INV;
}

// ---------------------------------------------------------------------------
// Kernel 4: neg_sim = q_n @ queue_n^T * (1/T), bf16 MFMA 16x16x32.
// 64(m) x 128(n) tile per 256-thread block (4 waves; wave w owns rows w*16..).
// MFMA operands SWAPPED: D[n][m] so acc reg index -> consecutive n (columns)
// => float4 stores. Grid: blockIdx.x = n-tile (fastest) so resident blocks
// sweep columns of one row band => streaming HBM writes, A-tile L2 reuse.
// Fused epilogue: per-row sum of exp(x - SHIFT), atomicAdd into row_sum.
constexpr int LDST = 136;  // 128 + 8 bf16 pad -> 2-way LDS conflicts only (free)
constexpr int BM = 64, BN = 128;

__global__ __launch_bounds__(256) void gemm_kernel(
        const ushort* __restrict__ q_bf, const ushort* __restrict__ queue_bf,
        float* __restrict__ neg_out, float* __restrict__ row_sum) {
    __shared__ __align__(16) ushort As[BM * LDST];   // 17.0 KB
    __shared__ __align__(16) ushort Bs[BN * LDST];   // 34.0 KB
    int t = threadIdx.x;
    int colBase = blockIdx.x * BN;   // 512 n-tiles, fastest-varying
    int rowBase = blockIdx.y * BM;   // 49 m-tiles

    // Stage A (64 q rows): 1024 chunks of 8 bf16
#pragma unroll
    for (int i = 0; i < 4; i++) {
        int chunk = t + i * 256;
        int r = chunk >> 4;
        int c8 = (chunk & 15) * 8;
        *(uint4*)(&As[r * LDST + c8]) =
            *(const uint4*)(q_bf + (size_t)(rowBase + r) * 128 + c8);
    }
    // Stage B (128 queue rows): 2048 chunks
#pragma unroll
    for (int i = 0; i < 8; i++) {
        int chunk = t + i * 256;
        int r = chunk >> 4;
        int c8 = (chunk & 15) * 8;
        *(uint4*)(&Bs[r * LDST + c8]) =
            *(const uint4*)(queue_bf + (size_t)(colBase + r) * 128 + c8);
    }
    __syncthreads();

    int wave = t >> 6, lane = t & 63;
    int m16 = lane & 15, quad = lane >> 4;
    floatx4 zero = {0.f, 0.f, 0.f, 0.f};
    floatx4 acc[8];
#pragma unroll
    for (int c = 0; c < 8; c++) acc[c] = zero;

#pragma unroll
    for (int k0 = 0; k0 < 128; k0 += 32) {
        // A-fragment for this wave's 16 rows (same layout as mfma-B operand:
        // lane holds Aq[m = lane&15][k0 + quad*8 + j])
        short8 a = *(const short8*)(&As[(wave * 16 + m16) * LDST + k0 + quad * 8]);
#pragma unroll
        for (int c = 0; c < 8; c++) {
            short8 bb = *(const short8*)(&Bs[(c * 16 + m16) * LDST + k0 + quad * 8]);
            // Swapped: D[n][m] = sum_k Bq[n][k] * Aq[m][k]
            acc[c] = __builtin_amdgcn_mfma_f32_16x16x32_bf16(bb, a, acc[c], 0, 0, 0);
        }
    }

    // Epilogue. D layout (verified m89/m91): col = lane&15 -> m, row = quad*4+reg -> n.
    // Lane owns row (rowBase + wave*16 + m16), cols {c*16 + quad*4 + 0..3}.
    int rowg = rowBase + wave * 16 + m16;
    float* rowptr = neg_out + (size_t)rowg * Q_ + colBase + quad * 4;
    float esum = 0.f;
#pragma unroll
    for (int c = 0; c < 8; c++) {
        floatx4 v;
        v[0] = acc[c][0] * TEMP_INV;
        v[1] = acc[c][1] * TEMP_INV;
        v[2] = acc[c][2] * TEMP_INV;
        v[3] = acc[c][3] * TEMP_INV;
        esum += __expf(v[0] - SHIFT) + __expf(v[1] - SHIFT)
              + __expf(v[2] - SHIFT) + __expf(v[3] - SHIFT);
        *(floatx4*)(rowptr + c * 16) = v;   // 16B-aligned float4 store
    }
    // All 32 of this lane's values belong to row `rowg`; combine the 4 quads.
    esum += __shfl_xor(esum, 16);
    esum += __shfl_xor(esum, 32);
    if (quad == 0) atomicAdd(&row_sum[rowg], esum);
}

// ---------------------------------------------------------------------------
// Kernel 5: loss = mean_i( log(row_sum_i + exp(pos_i-SHIFT)) + SHIFT - pos_i )
__global__ void loss_kernel(const float* __restrict__ pos,
                            const float* __restrict__ row_sum,
                            float* __restrict__ out_loss) {
    __shared__ float red[256];
    int t = threadIdx.x;
    float acc = 0.f;
    for (int i = t; i < M_; i += 256) {
        float p = pos[i];
        float total = row_sum[i] + __expf(p - SHIFT);
        acc += logf(total) + SHIFT - p;
    }
    red[t] = acc;
    __syncthreads();
    for (int s = 128; s; s >>= 1) {
        if (t < s) red[t] += red[t + s];
        __syncthreads();
    }
    if (t == 0) out_loss[0] = red[0] * (1.0f / (float)M_);
}

// ---------------------------------------------------------------------------
extern "C" void kernel_launch(void* const* d_in, const int* in_sizes, int n_in,
                              void* d_out, int out_size, void* d_ws, size_t ws_size,
                              hipStream_t stream) {
    const float* d1    = (const float*)d_in[0];  // dense_features_1 -> q
    const float* d2    = (const float*)d_in[1];  // dense_features_2 -> k
    // d_in[2], d_in[3] (backbone features) are unused by the reference
    const float* queue = (const float*)d_in[4];

    float* out     = (float*)d_out;
    float* pos_out = out + 1;            // [3136]
    float* neg_out = out + 1 + M_;       // [3136][65536]

    char* ws = (char*)d_ws;
    ushort* queue_bf = (ushort*)ws;                                   // 16 MB
    ushort* q_bf     = (ushort*)(ws + (size_t)Q_ * 128 * 2);          // 784 KB
    float*  q_f      = (float*)(ws + (size_t)Q_ * 128 * 2 + (size_t)M_ * 128 * 2);
    float*  k_f      = q_f + (size_t)M_ * 128;
    float*  row_sum  = k_f + (size_t)M_ * 128;                        // [3136]

    hipMemsetAsync(row_sum, 0, M_ * sizeof(float), stream);

    norm_queue_kernel<<<Q_ / 4, 256, 0, stream>>>(queue, queue_bf);
    norm_qk_kernel<<<(2 * M_) / 4, 256, 0, stream>>>(d1, d2, q_bf, q_f, k_f);
    possim_kernel<<<M_, 256, 0, stream>>>(q_f, k_f, pos_out);

    dim3 g(Q_ / BN, M_ / BM);  // (512 n-tiles fastest, 49 m-tiles)
    gemm_kernel<<<g, 256, 0, stream>>>(q_bf, queue_bf, neg_out, row_sum);

    loss_kernel<<<1, 256, 0, stream>>>(pos_out, row_sum, out);
}